// Round 2
// baseline (333.899 us; speedup 1.0000x reference)
//
#include <hip/hip_runtime.h>
#include <hip/hip_cooperative_groups.h>
#include <stdint.h>

namespace cg = cooperative_groups;

#define NIMG 32
#define H 1024
#define W 1024
#define BH 73
#define BW 73
#define NCHUNK (NIMG * BH)        // 2336 chunks; chunk = n*73 + by
#define TOTAL (NIMG * BH * BW)    // 170528
#define BS 14                     // block stride
#define KW 16                     // pool window
#define GRID 1024                 // 4 blocks/CU x 256 CU — exactly co-resident
#define NT 256
#define MAXC 3                    // ceil(NCHUNK / GRID)

// Single fused cooperative kernel:
//  phase 1: per-chunk 16x16/stride-14 max-pool -> flag (kept in registers),
//           per-chunk count -> global, prefill out with (32,73,73).
//  grid.sync()
//  phase 2: per-chunk exclusive prefix via block-parallel reduction over the
//           counts array (9 KB, L2-hot), ballot-based intra-chunk rank,
//           scatter (n,by,bx) triples; block 0 writes the total count.
__global__ __launch_bounds__(NT, 4) void fused_kernel(const float* __restrict__ mask,
                                                      int* __restrict__ counts,
                                                      int* __restrict__ out_idx) {
    int t = threadIdx.x;
    int bid = blockIdx.x;
    int lane = t & 63;
    int wave = t >> 6;
    __shared__ float colmax[W];
    __shared__ int sred[4];
    __shared__ int cbase;
    __shared__ int w0cnt;

    int flag[MAXC];

    // ---------------- phase 1: pool ----------------
    for (int it = 0; it < MAXC; ++it) {
        int chunk = bid + it * GRID;          // block-uniform condition
        flag[it] = 0;
        if (chunk < NCHUNK) {
            int n = chunk / BH;
            int by = chunk - n * BH;
            const float* img = mask + (size_t)n * (H * W);
            int y0 = by * BS - 1;
            int rstart = (y0 < 0) ? 1 : 0;    // skip zero-pad row for by==0
            float4 acc = make_float4(-INFINITY, -INFINITY, -INFINITY, -INFINITY);
            for (int r = rstart; r < KW; ++r) {
                float4 v = ((const float4*)(img + (size_t)(y0 + r) * W))[t];
                acc.x = fmaxf(acc.x, v.x);
                acc.y = fmaxf(acc.y, v.y);
                acc.z = fmaxf(acc.z, v.z);
                acc.w = fmaxf(acc.w, v.w);
            }
            __syncthreads();                  // colmax/sred reuse guard
            ((float4*)colmax)[t] = acc;
            __syncthreads();
            if (t < BW) {
                int x0 = t * BS - 1;
                float m = -INFINITY;
#pragma unroll
                for (int c = 0; c < KW; ++c) {
                    int x = x0 + c;
                    if (x >= 0) m = fmaxf(m, colmax[x]);   // x <= 1022 always
                }
                flag[it] = (m > 0.5f) ? 1 : 0;
                int s = (chunk * BW + t) * 3;  // prefill with fill triple
                out_idx[s]     = NIMG;
                out_idx[s + 1] = BH;
                out_idx[s + 2] = BW;
            }
            unsigned long long b = __ballot(flag[it]);
            if (lane == 0) sred[wave] = __popcll(b);
            __syncthreads();
            if (t == 0) counts[chunk] = sred[0] + sred[1] + sred[2] + sred[3];
        }
    }

    cg::this_grid().sync();

    // ---------------- phase 2: prefix + scatter ----------------
    for (int it = 0; it < MAXC; ++it) {
        int chunk = bid + it * GRID;
        if (chunk >= NCHUNK) break;           // block-uniform
        int n = chunk / BH;
        int by = chunk - n * BH;
        // exclusive prefix: block-parallel sum of counts[0..chunk)
        int local = 0;
        for (int i = t; i < chunk; i += NT) local += counts[i];
        local += __shfl_down(local, 32);
        local += __shfl_down(local, 16);
        local += __shfl_down(local, 8);
        local += __shfl_down(local, 4);
        local += __shfl_down(local, 2);
        local += __shfl_down(local, 1);
        __syncthreads();                      // sred reuse guard
        if (lane == 0) sred[wave] = local;
        unsigned long long b = __ballot(flag[it]);
        if (t == 0) w0cnt = __popcll(b);      // wave-0 active count
        __syncthreads();
        if (t == 0) cbase = sred[0] + sred[1] + sred[2] + sred[3];
        __syncthreads();
        int pos = __popcll(b & ((1ull << lane) - 1ull)) + ((t >= 64) ? w0cnt : 0);
        if (flag[it]) {
            int o = (cbase + pos) * 3;
            out_idx[o]     = n;
            out_idx[o + 1] = by;
            out_idx[o + 2] = t;
        }
    }

    // total count -> out[TOTAL*3] (block 0)
    if (bid == 0) {
        int local = 0;
        for (int i = t; i < NCHUNK; i += NT) local += counts[i];
        local += __shfl_down(local, 32);
        local += __shfl_down(local, 16);
        local += __shfl_down(local, 8);
        local += __shfl_down(local, 4);
        local += __shfl_down(local, 2);
        local += __shfl_down(local, 1);
        __syncthreads();
        if (lane == 0) sred[wave] = local;
        __syncthreads();
        if (t == 0) out_idx[(size_t)TOTAL * 3] = sred[0] + sred[1] + sred[2] + sred[3];
    }
}

extern "C" void kernel_launch(void* const* d_in, const int* in_sizes, int n_in,
                              void* d_out, int out_size, void* d_ws, size_t ws_size,
                              hipStream_t stream) {
    const float* mask = (const float*)d_in[0];
    int* out = (int*)d_out;
    int* counts = (int*)d_ws;

    void* args[] = {(void*)&mask, (void*)&counts, (void*)&out};
    hipLaunchCooperativeKernel((void*)fused_kernel, dim3(GRID), dim3(NT),
                               args, 0, stream);
}

// Round 4
// 192.248 us; speedup vs baseline: 1.7368x; 1.7368x over previous
//
#include <hip/hip_runtime.h>
#include <stdint.h>

#define NIMG 32
#define H 1024
#define W 1024
#define BH 73
#define BW 73
#define NCHUNK (NIMG * BH)        // 2336 chunks; chunk = n*73 + by
#define TOTAL (NIMG * BH * BW)    // 170528
#define BS 14                     // block stride
#define KW 16                     // pool window

// ---------------------------------------------------------------------------
// Kernel A: per-(n,by) strip max-pool. MLP fix: row loads issued in two
// batches of 8 fully-independent float4 loads (row index clamped to 0 — the
// duplicated row is a no-op under max). ~50 VGPR -> full occupancy, 2336
// blocks of TLP. Writes flags (1B/block), per-chunk counts, and prefills the
// output with the fill triple (32,73,73).
// ---------------------------------------------------------------------------
__global__ __launch_bounds__(256) void pool_kernel(const float* __restrict__ mask,
                                                   uint8_t* __restrict__ flags,
                                                   int* __restrict__ counts,
                                                   int* __restrict__ out_idx) {
    int chunk = blockIdx.x;
    int n  = chunk / BH;
    int by = chunk - n * BH;
    const float* img = mask + (size_t)n * (H * W);
    int t = threadIdx.x;
    int lane = t & 63;
    int wave = t >> 6;
    __shared__ float colmax[W];
    __shared__ int sred[4];

    int y0 = by * BS - 1;
    float4 v[8];
    // batch 0: rows 0..7 (clamped), 8 independent loads in flight
#pragma unroll
    for (int r = 0; r < 8; ++r) {
        int y = y0 + r;
        y = (y < 0) ? 0 : y;              // dup row 0: harmless under max
        v[r] = ((const float4*)(img + (size_t)y * W))[t];
    }
    float4 acc = v[0];
#pragma unroll
    for (int r = 1; r < 8; ++r) {
        acc.x = fmaxf(acc.x, v[r].x);
        acc.y = fmaxf(acc.y, v[r].y);
        acc.z = fmaxf(acc.z, v[r].z);
        acc.w = fmaxf(acc.w, v[r].w);
    }
    // batch 1: rows 8..15 (no clamp needed; y0+8 >= 7, y0+15 <= 1022)
#pragma unroll
    for (int r = 0; r < 8; ++r) {
        v[r] = ((const float4*)(img + (size_t)(y0 + 8 + r) * W))[t];
    }
#pragma unroll
    for (int r = 0; r < 8; ++r) {
        acc.x = fmaxf(acc.x, v[r].x);
        acc.y = fmaxf(acc.y, v[r].y);
        acc.z = fmaxf(acc.z, v[r].z);
        acc.w = fmaxf(acc.w, v[r].w);
    }
    ((float4*)colmax)[t] = acc;
    __syncthreads();

    int flag = 0;
    if (t < BW) {
        int x0 = t * BS - 1;
        float m = colmax[x0 < 0 ? 0 : x0];
#pragma unroll
        for (int c = 1; c < KW; ++c) {
            m = fmaxf(m, colmax[x0 + c]);  // x0+c in [0, 1022]
        }
        flag = (m > 0.5f) ? 1 : 0;
        flags[chunk * BW + t] = (uint8_t)flag;
    }
    // prefill this chunk's 219-int output region with (32,73,73)
    if (t < BW * 3) {
        int p = chunk * (BW * 3) + t;      // 219 % 3 == 0 -> p%3 == t%3
        out_idx[p] = ((t % 3) == 0) ? NIMG : BH;   // BH == BW == 73
    }
    unsigned long long b = __ballot(flag);
    if (lane == 0) sred[wave] = __popcll(b);
    __syncthreads();
    if (t == 0) counts[chunk] = sred[0] + sred[1] + sred[2] + sred[3];
}

// ---------------------------------------------------------------------------
// Kernel B: per-chunk exclusive prefix via block-parallel reduction over the
// 9 KB counts array (L2-hot), ballot rank, scatter triples. Block 0 also
// writes the total count.
// ---------------------------------------------------------------------------
__global__ __launch_bounds__(128) void scatter_kernel(const uint8_t* __restrict__ flags,
                                                      const int* __restrict__ counts,
                                                      int* __restrict__ out_idx) {
    int chunk = blockIdx.x;
    int n  = chunk / BH;
    int by = chunk - n * BH;
    int t = threadIdx.x;              // 0..127
    int lane = t & 63;
    int wave = t >> 6;
    __shared__ int sred[2];
    __shared__ int w0cnt;

    int flag = (t < BW) ? (int)flags[chunk * BW + t] : 0;

    // exclusive prefix: block-parallel sum of counts[0..chunk)
    int local = 0;
    for (int i = t; i < chunk; i += 128) local += counts[i];
    local += __shfl_down(local, 32);
    local += __shfl_down(local, 16);
    local += __shfl_down(local, 8);
    local += __shfl_down(local, 4);
    local += __shfl_down(local, 2);
    local += __shfl_down(local, 1);
    if (lane == 0) sred[wave] = local;
    unsigned long long b = __ballot(flag);
    if (t == 0) w0cnt = __popcll(b);
    __syncthreads();
    int cbase = sred[0] + sred[1];
    int pos = __popcll(b & ((1ull << lane) - 1ull)) + ((t >= 64) ? w0cnt : 0);
    if (flag) {
        int o = (cbase + pos) * 3;
        out_idx[o]     = n;
        out_idx[o + 1] = by;
        out_idx[o + 2] = t;
    }

    // total count -> out[TOTAL*3] (block 0 only)
    if (chunk == 0) {
        int tot = 0;
        for (int i = t; i < NCHUNK; i += 128) tot += counts[i];
        tot += __shfl_down(tot, 32);
        tot += __shfl_down(tot, 16);
        tot += __shfl_down(tot, 8);
        tot += __shfl_down(tot, 4);
        tot += __shfl_down(tot, 2);
        tot += __shfl_down(tot, 1);
        __syncthreads();
        if (lane == 0) sred[wave] = tot;
        __syncthreads();
        if (t == 0) out_idx[(size_t)TOTAL * 3] = sred[0] + sred[1];
    }
}

extern "C" void kernel_launch(void* const* d_in, const int* in_sizes, int n_in,
                              void* d_out, int out_size, void* d_ws, size_t ws_size,
                              hipStream_t stream) {
    const float* mask = (const float*)d_in[0];
    int* out = (int*)d_out;

    uint8_t* flags = (uint8_t*)d_ws;                    // 170528 B
    int* counts = (int*)((char*)d_ws + 170624);         // 2336 ints

    pool_kernel<<<NCHUNK, 256, 0, stream>>>(mask, flags, counts, out);
    scatter_kernel<<<NCHUNK, 128, 0, stream>>>(flags, counts, out);
}